// Round 19
// baseline (145.183 us; speedup 1.0000x reference)
//
#include <hip/hip_runtime.h>
#include <hip/hip_fp16.h>
#include <math.h>

// Problem constants
#define BATCH 256
#define CIN 3
#define HW 128
#define OC 16
#define POOLED 63
#define FEAT 63504         // OC*63*63
#define NH 256
#define FANIN 512
#define NO 10

#define PW 70              // LDS x-window in halves (even; lane stride 35 dwords == 3 mod 32 -> conflict-free)

typedef _Float16 h4 __attribute__((ext_vector_type(4)));
typedef _Float16 h2v __attribute__((ext_vector_type(2)));
typedef float    f4 __attribute__((ext_vector_type(4)));

// ---------------- Kernel 1: conv3x3+bias+relu+maxpool via MFMA, j-split ---------
// R18 accounting: conv ~30-35us vs ~17us floor; 51.5KB LDS -> 3 blocks/CU (12
// waves) and 3.94 block-generations -> stall-prone schedule. Split each block's
// j-range in half (x-window 70 halves): LDS 26,880B -> 6 blocks/CU, 24 waves/CU,
// grid 2016 (finer tail). Staging flattened (27 f2/thread, coalesced); compute
// 8 j/wave. NT stores + XCD g-pairing kept (R17-verified).
__global__ __launch_bounds__(256) void conv_pool_kernel(const float* __restrict__ inp,
                                                        const float* __restrict__ cw,
                                                        const float* __restrict__ cb,
                                                        __half* __restrict__ featsT) {
    __shared__ _Float16 sB[192 * PW];             // 26,880 B
    const int t    = threadIdx.x;
    const int l    = t & 63;
    const int w    = t >> 6;        // wave 0..3
    const int q    = l >> 4;        // quarter 0..3
    const int bcol = l & 15;        // oc for A, batch col for B/D

    // block decode: id -> u (XCD slot), jh (j-half), i (pooled row), g (b-group).
    // g-pairs (2u,2u+1) share featsT 64B lines AND the XCD (R10-verified).
    const int id = blockIdx.x;               // 0..2015
    const int u  = id & 7;
    const int v  = id >> 3;                  // 0..251
    const int jh = v & 1;                    // j-half
    const int tt = v >> 1;                   // 0..125
    const int i  = tt >> 1;                  // pooled row 0..62
    const int g  = 2 * u + (tt & 1);         // batch group 0..15
    const int y0 = 2 * i;
    const int xbase = 64 * jh;

    // ---- stage: 192 rows (c4*16+b_l) x 35 float2, flattened & coalesced ----
    for (int e = t; e < 192 * 35; e += 256) {
        const int r  = e / 35;               // rowslot 0..191 (magic-mul)
        const int xi = e - r * 35;           // 0..34
        const int gx = xbase + 2 * xi;
        if (gx <= 126) {
            const int c4 = r >> 4;           // c*4+dy, 0..11
            const int bl = r & 15;
            const int c  = c4 >> 2;
            const int dy = c4 & 3;
            const float2 vv = *(const float2*)
                &inp[((size_t)(g * 16 + bl) * CIN + c) * (HW * HW) + (y0 + dy) * HW + gx];
            *(__half2*)&sB[(size_t)r * PW + (gx - xbase)] = __float22half2_rn(vv);
        }
    }
    __syncthreads();

    // ---- per-lane A fragments and B base offsets (R12 k-permute mapping) ----
    h4  aF[3][2];
    int bOff[3][2];
    float bias[4];
#pragma unroll
    for (int s = 0; s < 3; ++s) {
        const int rIdx = s * 4 + q;
        const int c    = (rIdx * 11) >> 5;   // /3
        const int ky   = rIdx - 3 * c;
        const bool valid = (c < 3);
        float wv[3];
#pragma unroll
        for (int kx = 0; kx < 3; ++kx)
            wv[kx] = valid ? cw[(bcol * CIN + c) * 9 + ky * 3 + kx] : 0.0f;
        aF[s][0][0] = (_Float16)wv[0]; aF[s][0][1] = (_Float16)wv[1];
        aF[s][0][2] = (_Float16)wv[2]; aF[s][0][3] = (_Float16)0.0f;
        aF[s][1][0] = (_Float16)0.0f;  aF[s][1][1] = (_Float16)wv[0];
        aF[s][1][2] = (_Float16)wv[1]; aF[s][1][3] = (_Float16)wv[2];
#pragma unroll
        for (int ys = 0; ys < 2; ++ys) {
            const int row = valid ? (c * 4 + ys + ky) : ys;
            bOff[s][ys] = (row * 16 + bcol) * PW;
        }
    }
#pragma unroll
    for (int r = 0; r < 4; ++r) bias[r] = cb[4 * q + r];

    // ---- j loop: wave w owns 8 js of this half ----
    const int jbeg = 32 * jh + 8 * w;
#pragma unroll 1
    for (int jl = 0; jl < 8; ++jl) {
        const int j = jbeg + jl;
        if (j > 62) break;                   // only trims wave3 of jh=1
        const int xl = 2 * j - xbase;        // local x 0..63

        f4 d00 = {0.f,0.f,0.f,0.f}, d01 = d00, d10 = d00, d11 = d00;
#pragma unroll
        for (int s = 0; s < 3; ++s) {
            const _Float16* p0 = &sB[bOff[s][0] + xl];
            const _Float16* p1 = &sB[bOff[s][1] + xl];
            const h2v a0 = *(const h2v*)p0, a1 = *(const h2v*)(p0 + 2);
            const h2v c0 = *(const h2v*)p1, c1 = *(const h2v*)(p1 + 2);
            const h4 bF0 = {a0[0], a0[1], a1[0], a1[1]};
            const h4 bF1 = {c0[0], c0[1], c1[0], c1[1]};
            d00 = __builtin_amdgcn_mfma_f32_16x16x16f16(aF[s][0], bF0, d00, 0, 0, 0);
            d01 = __builtin_amdgcn_mfma_f32_16x16x16f16(aF[s][1], bF0, d01, 0, 0, 0);
            d10 = __builtin_amdgcn_mfma_f32_16x16x16f16(aF[s][0], bF1, d10, 0, 0, 0);
            d11 = __builtin_amdgcn_mfma_f32_16x16x16f16(aF[s][1], bF1, d11, 0, 0, 0);
        }
#pragma unroll
        for (int r = 0; r < 4; ++r) {
            const float mv = fmaxf(fmaxf(d00[r], d01[r]), fmaxf(d10[r], d11[r]));
            const float rv = fmaxf(mv + bias[r], 0.0f);
            const int oc = 4 * q + r;
            const __half hv = __float2half_rn(rv);
            __builtin_nontemporal_store(
                *(const short*)&hv,
                (short*)&featsT[(size_t)(oc * 3969 + i * POOLED + j) * BATCH + g * 16 + bcol]);
        }
    }
}

// ---------------- Kernel 2: sparse hidden layer, 16B gather (FROZEN R17) --------
__global__ __launch_bounds__(256) void hidden_kernel(const __half* __restrict__ featsT,
                                                     const int* __restrict__ hidx,
                                                     const float* __restrict__ hw,
                                                     float* __restrict__ hiddenP) {
    __shared__ int   sidx[128];
    __shared__ float swt[128];
    __shared__ float red[4][256];
    const int h = blockIdx.x;
    const int q = blockIdx.y;
    const int t = threadIdx.x;
    if (t < 128) {
        sidx[t] = hidx[h * FANIN + q * 128 + t];
        swt[t]  = hw[h * FANIN + q * 128 + t];
    }
    __syncthreads();

    const int l   = t & 63;
    const int w   = t >> 6;
    const int hl  = l & 31;
    const int sel = l >> 5;
    float acc[8] = {0.f,0.f,0.f,0.f,0.f,0.f,0.f,0.f};
#pragma unroll
    for (int m = 0; m < 16; ++m) {
        const int kloc = w * 32 + 2 * m + sel;
        const uint4 v = *(const uint4*)(featsT + (size_t)sidx[kloc] * BATCH + 8 * hl);
        const __half2* hp = reinterpret_cast<const __half2*>(&v);
        const float wt = swt[kloc];
#pragma unroll
        for (int d2 = 0; d2 < 4; ++d2) {
            const float2 f = __half22float2(hp[d2]);
            acc[2 * d2 + 0] += f.x * wt;
            acc[2 * d2 + 1] += f.y * wt;
        }
    }
#pragma unroll
    for (int e = 0; e < 8; ++e) acc[e] += __shfl_xor(acc[e], 32);
    if (sel == 0) {
#pragma unroll
        for (int e = 0; e < 8; ++e) red[w][8 * hl + e] = acc[e];
    }
    __syncthreads();

    if (t < 256) {
        const float s = red[0][t] + red[1][t] + red[2][t] + red[3][t];
        hiddenP[((size_t)q * NH + h) * BATCH + t] = s;
    }
}

// ---------------- Kernel 3: partial-sum + sigmoid + dense 256->10 (FROZEN R17) --
__global__ __launch_bounds__(256) void out_kernel(const float* __restrict__ hiddenP,
                                                  const float* __restrict__ hb,
                                                  const float* __restrict__ ow,
                                                  const float* __restrict__ ob,
                                                  float* __restrict__ out) {
    __shared__ float red[256];
    const int o  = blockIdx.x;
    const int bt = blockIdx.y;
    const int tb = threadIdx.x & 15;
    const int hg = threadIdx.x >> 4;
    const int b  = bt * 16 + tb;
    float acc = 0.f;
#pragma unroll
    for (int k = 0; k < 16; ++k) {
        const int h = hg * 16 + k;
        const float s = hiddenP[(0 * NH + h) * BATCH + b]
                      + hiddenP[(1 * NH + h) * BATCH + b]
                      + hiddenP[(2 * NH + h) * BATCH + b]
                      + hiddenP[(3 * NH + h) * BATCH + b] + hb[h];
        const float hs = 1.0f / (1.0f + __expf(-s));
        acc += hs * ow[o * NH + h];
    }
    red[threadIdx.x] = acc;
    __syncthreads();
    if (hg == 0) {
        float s = 0.f;
#pragma unroll
        for (int gg = 0; gg < 16; ++gg) s += red[gg * 16 + tb];
        out[b * NO + o] = 1.0f / (1.0f + __expf(-(s + ob[o])));
    }
}

extern "C" void kernel_launch(void* const* d_in, const int* in_sizes, int n_in,
                              void* d_out, int out_size, void* d_ws, size_t ws_size,
                              hipStream_t stream) {
    const float* inputs   = (const float*)d_in[0];
    const float* conv_w   = (const float*)d_in[1];
    const float* conv_b   = (const float*)d_in[2];
    const int*   hidden_i = (const int*)d_in[3];
    const float* hidden_w = (const float*)d_in[4];
    const float* hidden_b = (const float*)d_in[5];
    const float* out_w    = (const float*)d_in[6];
    const float* out_b    = (const float*)d_in[7];
    float* out = (float*)d_out;

    char* ws = (char*)d_ws;
    __half* featsT  = (__half*)ws;                                  // 32,514,048 B
    float*  hiddenP = (float*)(ws + (size_t)FEAT * BATCH * 2);      //  1,048,576 B

    conv_pool_kernel<<<2016, 256, 0, stream>>>(inputs, conv_w, conv_b, featsT);
    hidden_kernel<<<dim3(NH, 4), 256, 0, stream>>>(featsT, hidden_i, hidden_w, hiddenP);
    out_kernel<<<dim3(NO, 16), 256, 0, stream>>>(hiddenP, hidden_b, out_w, out_b, out);
}

// Round 20
// 132.336 us; speedup vs baseline: 1.0971x; 1.0971x over previous
//
#include <hip/hip_runtime.h>
#include <hip/hip_fp16.h>
#include <math.h>

// Problem constants
#define BATCH 256
#define CIN 3
#define HW 128
#define OC 16
#define POOLED 63
#define FEAT 63504         // OC*63*63
#define NH 256
#define FANIN 512
#define NO 10

#define PADX 134           // LDS x-stride in halves
#define ROWS 12            // (c,dy) rows

typedef _Float16 h4 __attribute__((ext_vector_type(4)));
typedef _Float16 h2v __attribute__((ext_vector_type(2)));
typedef float    f4 __attribute__((ext_vector_type(4)));

// ---------------- Kernel 1: conv3x3+bias+relu+maxpool via MFMA + NT stores -------
// R17 structure (best: 129.6us) with ONE change: staging via float4 (24 x 16B
// loads/thread, was 48 x 8B). 32 consecutive lanes cover one full 512B input
// row -> perfectly coalesced; halves global-load issue count + 64b addr chains
// in the phase R19 proved is the sensitive one (2x staging instrs = +26us).
// NT stores kept (R17: -5.4us, featsT lands clean in L3). XCD g-pairing kept.
__global__ __launch_bounds__(256) void conv_pool_kernel(const float* __restrict__ inp,
                                                        const float* __restrict__ cw,
                                                        const float* __restrict__ cb,
                                                        __half* __restrict__ featsT) {
    __shared__ _Float16 sB[ROWS * 16 * PADX];     // 51,456 B
    const int t    = threadIdx.x;
    const int l    = t & 63;
    const int w    = t >> 6;        // wave 0..3
    const int q    = l >> 4;        // quarter 0..3
    const int bcol = l & 15;        // oc for A/D, batch-col for B

    // block decode: g-pairs (2u,2u+1) share featsT 64B lines AND the XCD
    const int id = blockIdx.x;
    const int u  = id & 7;
    const int v  = id >> 3;          // 0..125
    const int i  = v >> 1;           // pooled row 0..62
    const int g  = 2 * u + (v & 1);  // batch group 0..15
    const int y0 = 2 * i;

    // ---- stage: 192 rows x 32 float4, 24 per thread, coalesced along x ----
#pragma unroll
    for (int it = 0; it < 24; ++it) {
        const int e  = t + 256 * it;     // 0..6143
        const int r  = e >> 5;           // row slot 0..191
        const int x4 = e & 31;           // float4 index within row
        const int c4 = r >> 4;           // (c*4+dy) 0..11
        const int bl = r & 15;
        const int c  = c4 >> 2;
        const int dy = c4 & 3;
        const float4 vv = *(const float4*)
            &inp[((size_t)(g * 16 + bl) * CIN + c) * (HW * HW) + (y0 + dy) * HW + 4 * x4];
        const size_t base = (size_t)(c4 * 16 + bl) * PADX + 4 * x4;
        *(__half2*)&sB[base + 0] = __float22half2_rn(make_float2(vv.x, vv.y));
        *(__half2*)&sB[base + 2] = __float22half2_rn(make_float2(vv.z, vv.w));
    }
    __syncthreads();

    // ---- per-lane A fragments and B base offsets (R12 k-permute mapping) ----
    h4  aF[3][2];
    int bOff[3][2];
    float bias[4];
#pragma unroll
    for (int s = 0; s < 3; ++s) {
        const int rIdx = s * 4 + q;
        const int c    = (rIdx * 11) >> 5;   // /3
        const int ky   = rIdx - 3 * c;
        const bool valid = (c < 3);
        float wv[3];
#pragma unroll
        for (int kx = 0; kx < 3; ++kx)
            wv[kx] = valid ? cw[(bcol * CIN + c) * 9 + ky * 3 + kx] : 0.0f;
        aF[s][0][0] = (_Float16)wv[0]; aF[s][0][1] = (_Float16)wv[1];
        aF[s][0][2] = (_Float16)wv[2]; aF[s][0][3] = (_Float16)0.0f;
        aF[s][1][0] = (_Float16)0.0f;  aF[s][1][1] = (_Float16)wv[0];
        aF[s][1][2] = (_Float16)wv[1]; aF[s][1][3] = (_Float16)wv[2];
#pragma unroll
        for (int ys = 0; ys < 2; ++ys) {
            const int row = valid ? (c * 4 + ys + ky) : ys;
            bOff[s][ys] = (row * 16 + bcol) * PADX;
        }
    }
#pragma unroll
    for (int r = 0; r < 4; ++r) bias[r] = cb[4 * q + r];

    // ---- pooled-col loop ----
    const int jend = (16 * w + 16 < 63) ? (16 * w + 16) : 63;
    for (int j = 16 * w; j < jend; ++j) {
        f4 d00 = {0.f,0.f,0.f,0.f}, d01 = d00, d10 = d00, d11 = d00;
#pragma unroll
        for (int s = 0; s < 3; ++s) {
            const _Float16* p0 = &sB[bOff[s][0] + 2 * j];
            const _Float16* p1 = &sB[bOff[s][1] + 2 * j];
            const h2v a0 = *(const h2v*)p0, a1 = *(const h2v*)(p0 + 2);
            const h2v c0 = *(const h2v*)p1, c1 = *(const h2v*)(p1 + 2);
            const h4 bF0 = {a0[0], a0[1], a1[0], a1[1]};
            const h4 bF1 = {c0[0], c0[1], c1[0], c1[1]};
            d00 = __builtin_amdgcn_mfma_f32_16x16x16f16(aF[s][0], bF0, d00, 0, 0, 0);
            d01 = __builtin_amdgcn_mfma_f32_16x16x16f16(aF[s][1], bF0, d01, 0, 0, 0);
            d10 = __builtin_amdgcn_mfma_f32_16x16x16f16(aF[s][0], bF1, d10, 0, 0, 0);
            d11 = __builtin_amdgcn_mfma_f32_16x16x16f16(aF[s][1], bF1, d11, 0, 0, 0);
        }
#pragma unroll
        for (int r = 0; r < 4; ++r) {
            const float mv = fmaxf(fmaxf(d00[r], d01[r]), fmaxf(d10[r], d11[r]));
            const float rv = fmaxf(mv + bias[r], 0.0f);
            const int oc = 4 * q + r;
            const __half hv = __float2half_rn(rv);
            __builtin_nontemporal_store(
                *(const short*)&hv,
                (short*)&featsT[(size_t)(oc * 3969 + i * POOLED + j) * BATCH + g * 16 + bcol]);
        }
    }
}

// ---------------- Kernel 2: sparse hidden layer, 16B gather (FROZEN R17) --------
__global__ __launch_bounds__(256) void hidden_kernel(const __half* __restrict__ featsT,
                                                     const int* __restrict__ hidx,
                                                     const float* __restrict__ hw,
                                                     float* __restrict__ hiddenP) {
    __shared__ int   sidx[128];
    __shared__ float swt[128];
    __shared__ float red[4][256];
    const int h = blockIdx.x;
    const int q = blockIdx.y;
    const int t = threadIdx.x;
    if (t < 128) {
        sidx[t] = hidx[h * FANIN + q * 128 + t];
        swt[t]  = hw[h * FANIN + q * 128 + t];
    }
    __syncthreads();

    const int l   = t & 63;
    const int w   = t >> 6;
    const int hl  = l & 31;
    const int sel = l >> 5;
    float acc[8] = {0.f,0.f,0.f,0.f,0.f,0.f,0.f,0.f};
#pragma unroll
    for (int m = 0; m < 16; ++m) {
        const int kloc = w * 32 + 2 * m + sel;
        const uint4 v = *(const uint4*)(featsT + (size_t)sidx[kloc] * BATCH + 8 * hl);
        const __half2* hp = reinterpret_cast<const __half2*>(&v);
        const float wt = swt[kloc];
#pragma unroll
        for (int d2 = 0; d2 < 4; ++d2) {
            const float2 f = __half22float2(hp[d2]);
            acc[2 * d2 + 0] += f.x * wt;
            acc[2 * d2 + 1] += f.y * wt;
        }
    }
#pragma unroll
    for (int e = 0; e < 8; ++e) acc[e] += __shfl_xor(acc[e], 32);
    if (sel == 0) {
#pragma unroll
        for (int e = 0; e < 8; ++e) red[w][8 * hl + e] = acc[e];
    }
    __syncthreads();

    if (t < 256) {
        const float s = red[0][t] + red[1][t] + red[2][t] + red[3][t];
        hiddenP[((size_t)q * NH + h) * BATCH + t] = s;
    }
}

// ---------------- Kernel 3: partial-sum + sigmoid + dense 256->10 (FROZEN R17) --
__global__ __launch_bounds__(256) void out_kernel(const float* __restrict__ hiddenP,
                                                  const float* __restrict__ hb,
                                                  const float* __restrict__ ow,
                                                  const float* __restrict__ ob,
                                                  float* __restrict__ out) {
    __shared__ float red[256];
    const int o  = blockIdx.x;
    const int bt = blockIdx.y;
    const int tb = threadIdx.x & 15;
    const int hg = threadIdx.x >> 4;
    const int b  = bt * 16 + tb;
    float acc = 0.f;
#pragma unroll
    for (int k = 0; k < 16; ++k) {
        const int h = hg * 16 + k;
        const float s = hiddenP[(0 * NH + h) * BATCH + b]
                      + hiddenP[(1 * NH + h) * BATCH + b]
                      + hiddenP[(2 * NH + h) * BATCH + b]
                      + hiddenP[(3 * NH + h) * BATCH + b] + hb[h];
        const float hs = 1.0f / (1.0f + __expf(-s));
        acc += hs * ow[o * NH + h];
    }
    red[threadIdx.x] = acc;
    __syncthreads();
    if (hg == 0) {
        float s = 0.f;
#pragma unroll
        for (int gg = 0; gg < 16; ++gg) s += red[gg * 16 + tb];
        out[b * NO + o] = 1.0f / (1.0f + __expf(-(s + ob[o])));
    }
}

extern "C" void kernel_launch(void* const* d_in, const int* in_sizes, int n_in,
                              void* d_out, int out_size, void* d_ws, size_t ws_size,
                              hipStream_t stream) {
    const float* inputs   = (const float*)d_in[0];
    const float* conv_w   = (const float*)d_in[1];
    const float* conv_b   = (const float*)d_in[2];
    const int*   hidden_i = (const int*)d_in[3];
    const float* hidden_w = (const float*)d_in[4];
    const float* hidden_b = (const float*)d_in[5];
    const float* out_w    = (const float*)d_in[6];
    const float* out_b    = (const float*)d_in[7];
    float* out = (float*)d_out;

    char* ws = (char*)d_ws;
    __half* featsT  = (__half*)ws;                                  // 32,514,048 B
    float*  hiddenP = (float*)(ws + (size_t)FEAT * BATCH * 2);      //  1,048,576 B

    conv_pool_kernel<<<1008, 256, 0, stream>>>(inputs, conv_w, conv_b, featsT);
    hidden_kernel<<<dim3(NH, 4), 256, 0, stream>>>(featsT, hidden_i, hidden_w, hiddenP);
    out_kernel<<<dim3(NO, 16), 256, 0, stream>>>(hiddenP, hidden_b, out_w, out_b, out);
}